// Round 1
// baseline (1359.440 us; speedup 1.0000x reference)
//
#include <hip/hip_runtime.h>
#include <stdint.h>

// Transformer prefill: B=2,S=1024,V=32000,D=1024,H=16,L=4,DK=64,DF=4096
#define B_ 2
#define S_ 1024
#define V_ 32000
#define D_ 1024
#define H_ 16
#define L_ 4
#define DF_ 4096
#define M_ (B_*S_)

typedef short short8 __attribute__((ext_vector_type(8)));
typedef float f32x4 __attribute__((ext_vector_type(4)));

__device__ __forceinline__ unsigned short f2bf(float f){
  union { float f; unsigned int u; } v; v.f = f;
  unsigned int u = v.u;
  u = u + 0x7fffu + ((u >> 16) & 1u);
  return (unsigned short)(u >> 16);
}

__device__ __forceinline__ void gload16(const void* g, void* l){
  __builtin_amdgcn_global_load_lds(
      (__attribute__((address_space(1))) void*)(uintptr_t)g,
      (__attribute__((address_space(3))) void*)(uintptr_t)l, 16, 0, 0);
}

// ---------------- embed gather: x[row] = emb[ids[row]] (f32) ----------------
__global__ __launch_bounds__(256) void embed_k(const int* __restrict__ ids,
    const float* __restrict__ emb, float* __restrict__ x){
  int row = blockIdx.x;
  int id = ids[row];
  float4 v = reinterpret_cast<const float4*>(emb + (size_t)id*D_)[threadIdx.x];
  reinterpret_cast<float4*>(x + (size_t)row*D_)[threadIdx.x] = v;
}

// ---------------- layernorm row kernel: f32 in -> bf16 out ----------------
__global__ __launch_bounds__(256) void ln_k(const float* __restrict__ x,
    const float* __restrict__ g, const float* __restrict__ b,
    unsigned short* __restrict__ out){
  int row = blockIdx.x;
  int tid = threadIdx.x;
  float4 v = reinterpret_cast<const float4*>(x + (size_t)row*D_)[tid];
  float s = v.x+v.y+v.z+v.w;
  float ss = v.x*v.x + v.y*v.y + v.z*v.z + v.w*v.w;
  #pragma unroll
  for (int off=1; off<64; off<<=1){ s += __shfl_xor(s, off); ss += __shfl_xor(ss, off); }
  __shared__ float rs[4], rss[4];
  int wave = tid>>6, lane = tid&63;
  if (lane==0){ rs[wave]=s; rss[wave]=ss; }
  __syncthreads();
  s  = rs[0]+rs[1]+rs[2]+rs[3];
  ss = rss[0]+rss[1]+rss[2]+rss[3];
  float mean = s * (1.0f/(float)D_);
  float var  = ss * (1.0f/(float)D_) - mean*mean;
  float inv = rsqrtf(var + 1e-5f);
  float4 gg = reinterpret_cast<const float4*>(g)[tid];
  float4 bb = reinterpret_cast<const float4*>(b)[tid];
  ushort4 o;
  o.x = f2bf((v.x-mean)*inv*gg.x + bb.x);
  o.y = f2bf((v.y-mean)*inv*gg.y + bb.y);
  o.z = f2bf((v.z-mean)*inv*gg.z + bb.z);
  o.w = f2bf((v.w-mean)*inv*gg.w + bb.w);
  reinterpret_cast<ushort4*>(out + (size_t)row*D_)[tid] = o;
}

// ---------------- transpose + f32->bf16: in [K][N] -> out [N][K] ----------------
__global__ __launch_bounds__(256) void transpose_k(const float* __restrict__ in,
    unsigned short* __restrict__ out, int K, int N, size_t in_ls, size_t out_ls){
  __shared__ float t[32][33];
  const float* inp = in + (size_t)blockIdx.z*in_ls;
  unsigned short* outp = out + (size_t)blockIdx.z*out_ls;
  int tx = threadIdx.x & 31, ty = threadIdx.x >> 5;
  int k0 = blockIdx.y*32, n0 = blockIdx.x*32;
  #pragma unroll
  for (int i=0;i<4;i++) t[ty+i*8][tx] = inp[(size_t)(k0+ty+i*8)*N + n0+tx];
  __syncthreads();
  #pragma unroll
  for (int i=0;i<4;i++) outp[(size_t)(n0+ty+i*8)*K + k0+tx] = f2bf(t[tx][ty+i*8]);
}

// ---------------- GEMM: C[M,N] = A[M,K](bf16) @ B_T[N,K](bf16)^T ----------------
// EP: 0 = write bf16; 1 = +resid write f32; 2 = +bias,GELU write bf16;
//     3 = +bias,+resid write f32; 4 = write f32
template<int EP>
__global__ __launch_bounds__(256)
void gemm_bt(const unsigned short* __restrict__ A, const unsigned short* __restrict__ B,
             void* __restrict__ C, const float* __restrict__ bias,
             const float* __restrict__ resid, int K, int ldc){
  __shared__ unsigned short As[128*64];
  __shared__ unsigned short Bs[128*64];
  const int tid = threadIdx.x;
  const int wave = tid>>6, lane = tid&63;
  const int wm = wave>>1, wn = wave&1;
  const int row0 = blockIdx.y*128, col0 = blockIdx.x*128;
  f32x4 acc[4][4] = {};
  const unsigned short* Ag = A + (size_t)(row0 + wave*8 + (lane>>3))*K + (lane&7)*8;
  const unsigned short* Bg = B + (size_t)(col0 + wave*8 + (lane>>3))*K + (lane&7)*8;
  unsigned short* Asb = As + (wave*8)*64;
  unsigned short* Bsb = Bs + (wave*8)*64;
  const int r = lane&15, g16 = lane>>4;
  for (int kt=0; kt<K; kt+=64){
    #pragma unroll
    for (int i=0;i<4;i++){
      gload16(Ag + (size_t)i*32*K + kt, Asb + i*32*64);
      gload16(Bg + (size_t)i*32*K + kt, Bsb + i*32*64);
    }
    __syncthreads();
    #pragma unroll
    for (int ks=0; ks<2; ks++){
      short8 a[4], b[4];
      #pragma unroll
      for (int m=0;m<4;m++)
        a[m] = *reinterpret_cast<const short8*>(As + (wm*64+m*16+r)*64 + ks*32 + g16*8);
      #pragma unroll
      for (int n=0;n<4;n++)
        b[n] = *reinterpret_cast<const short8*>(Bs + (wn*64+n*16+r)*64 + ks*32 + g16*8);
      #pragma unroll
      for (int m=0;m<4;m++)
        #pragma unroll
        for (int n=0;n<4;n++)
          acc[m][n] = __builtin_amdgcn_mfma_f32_16x16x32_bf16(a[m], b[n], acc[m][n], 0,0,0);
    }
    __syncthreads();
  }
  #pragma unroll
  for (int m=0;m<4;m++){
    const int row = row0 + wm*64 + m*16 + g16*4;
    #pragma unroll
    for (int n=0;n<4;n++){
      const int col = col0 + wn*64 + n*16 + r;
      #pragma unroll
      for (int j=0;j<4;j++){
        float val = acc[m][n][j];
        size_t idx = (size_t)(row+j)*ldc + col;
        if constexpr (EP==2 || EP==3) val += bias[col];
        if constexpr (EP==2) val = 0.5f*val*(1.0f + erff(val*0.70710678118f));
        if constexpr (EP==1 || EP==3) val += resid[idx];
        if constexpr (EP==0 || EP==2) ((unsigned short*)C)[idx] = f2bf(val);
        else ((float*)C)[idx] = val;
      }
    }
  }
}

// ---------------- fused causal attention (flash-style) ----------------
// qkv: [M_][3*D_] bf16 (q | k | v), o: [M_][D_] bf16
__global__ __launch_bounds__(256)
void attn_k(const unsigned short* __restrict__ qkv, unsigned short* __restrict__ o){
  __shared__ unsigned short Ks[64*64];
  __shared__ unsigned short Vt[64*64];
  __shared__ unsigned short Ps[4*16*64];
  const int tid = threadIdx.x;
  const int wave = tid>>6, lane = tid&63;
  const int qb = blockIdx.x, h = blockIdx.y, b = blockIdx.z;
  const int r = lane&15, g = lane>>4;
  const size_t rowbase = (size_t)b*S_*3*D_;
  short8 qf[2];
  {
    const unsigned short* qp = qkv + rowbase + (size_t)(qb*64 + wave*16 + r)*(3*D_) + h*64 + g*8;
    qf[0] = *reinterpret_cast<const short8*>(qp);
    qf[1] = *reinterpret_cast<const short8*>(qp + 32);
  }
  float mrow[4] = {-INFINITY,-INFINITY,-INFINITY,-INFINITY};
  float lrow[4] = {0.f,0.f,0.f,0.f};
  f32x4 oacc[4] = {};
  const int qglob0 = qb*64 + wave*16 + g*4;
  unsigned short* Pw = Ps + wave*16*64;

  for (int kt=0; kt<=qb; kt++){
    __syncthreads();
    #pragma unroll
    for (int i=0;i<2;i++){
      int key = i*32 + (tid>>3);
      int c8 = (tid&7)*8;
      const unsigned short* kp = qkv + rowbase + (size_t)(kt*64+key)*(3*D_) + D_ + h*64 + c8;
      uint4 kd = *reinterpret_cast<const uint4*>(kp);
      int bo = (key*128 + c8*2) ^ ((key&7)<<4);
      *reinterpret_cast<uint4*>((char*)Ks + bo) = kd;
      const unsigned short* vp = qkv + rowbase + (size_t)(kt*64+key)*(3*D_) + 2*D_ + h*64 + c8;
      uint4 vd = *reinterpret_cast<const uint4*>(vp);
      const unsigned short* ve = reinterpret_cast<const unsigned short*>(&vd);
      #pragma unroll
      for (int j=0;j<8;j++){
        int d = c8 + j;
        int bo2 = (d*128 + key*2) ^ ((d&7)<<4);
        *reinterpret_cast<unsigned short*>((char*)Vt + bo2) = ve[j];
      }
    }
    __syncthreads();
    // QK^T -> per-lane scores for q rows (g*4+j), keys (nb*16+r)
    f32x4 sacc[4] = {};
    #pragma unroll
    for (int ks=0; ks<2; ks++){
      #pragma unroll
      for (int nb=0; nb<4; nb++){
        int key = nb*16 + r;
        int bo = (key*128 + (ks*32+g*8)*2) ^ ((key&7)<<4);
        short8 kf = *reinterpret_cast<const short8*>((char*)Ks + bo);
        sacc[nb] = __builtin_amdgcn_mfma_f32_16x16x32_bf16(qf[ks], kf, sacc[nb], 0,0,0);
      }
    }
    float sv[4][4];
    float tm[4] = {-INFINITY,-INFINITY,-INFINITY,-INFINITY};
    #pragma unroll
    for (int nb=0; nb<4; nb++){
      int key = kt*64 + nb*16 + r;
      #pragma unroll
      for (int j=0;j<4;j++){
        float s = sacc[nb][j]*0.125f;
        s = (key <= qglob0 + j) ? s : -INFINITY;
        sv[nb][j] = s;
        tm[j] = fmaxf(tm[j], s);
      }
    }
    #pragma unroll
    for (int off=1; off<16; off<<=1){
      #pragma unroll
      for (int j=0;j<4;j++) tm[j] = fmaxf(tm[j], __shfl_xor(tm[j], off));
    }
    float sf[4], psum[4];
    #pragma unroll
    for (int j=0;j<4;j++){
      float mn = fmaxf(mrow[j], tm[j]);
      sf[j] = __expf(mrow[j]-mn);
      mrow[j] = mn;
      psum[j] = 0.0f;
    }
    #pragma unroll
    for (int nb=0; nb<4; nb++){
      #pragma unroll
      for (int j=0;j<4;j++){
        float p = __expf(sv[nb][j]-mrow[j]);
        psum[j] += p;
        int prow = g*4+j;
        int bo = (prow*128 + (nb*16+r)*2) ^ ((prow&7)<<4);
        *reinterpret_cast<unsigned short*>((char*)Pw + bo) = f2bf(p);
      }
    }
    #pragma unroll
    for (int off=1; off<16; off<<=1){
      #pragma unroll
      for (int j=0;j<4;j++) psum[j] += __shfl_xor(psum[j], off);
    }
    #pragma unroll
    for (int j=0;j<4;j++) lrow[j] = lrow[j]*sf[j] + psum[j];
    #pragma unroll
    for (int nb=0;nb<4;nb++){
      #pragma unroll
      for (int j=0;j<4;j++) oacc[nb][j] *= sf[j];
    }
    asm volatile("s_waitcnt lgkmcnt(0)" ::: "memory");
    // PV: A = P [16q x 64key], B = V^T
    #pragma unroll
    for (int ks=0; ks<2; ks++){
      int bo = (r*128 + (ks*32+g*8)*2) ^ ((r&7)<<4);
      short8 pf = *reinterpret_cast<const short8*>((char*)Pw + bo);
      #pragma unroll
      for (int nb=0; nb<4; nb++){
        int d = nb*16 + r;
        int bo2 = (d*128 + (ks*32+g*8)*2) ^ ((d&7)<<4);
        short8 vf = *reinterpret_cast<const short8*>((char*)Vt + bo2);
        oacc[nb] = __builtin_amdgcn_mfma_f32_16x16x32_bf16(pf, vf, oacc[nb], 0,0,0);
      }
    }
  }
  #pragma unroll
  for (int nb=0; nb<4; nb++){
    #pragma unroll
    for (int j=0;j<4;j++){
      float ov = oacc[nb][j] / lrow[j];
      size_t row = (size_t)b*S_ + qb*64 + wave*16 + g*4 + j;
      o[row*D_ + h*64 + nb*16 + r] = f2bf(ov);
    }
  }
}

extern "C" void kernel_launch(void* const* d_in, const int* in_sizes, int n_in,
                              void* d_out, int out_size, void* d_ws, size_t ws_size,
                              hipStream_t stream) {
  const int*   ids   = (const int*)  d_in[0];
  const float* emb   = (const float*)d_in[1];
  const float* Wq    = (const float*)d_in[2];
  const float* Wk    = (const float*)d_in[3];
  const float* Wv    = (const float*)d_in[4];
  const float* Wo    = (const float*)d_in[5];
  const float* W1    = (const float*)d_in[6];
  const float* b1    = (const float*)d_in[7];
  const float* W2    = (const float*)d_in[8];
  const float* b2    = (const float*)d_in[9];
  const float* ln1_g = (const float*)d_in[10];
  const float* ln1_b = (const float*)d_in[11];
  const float* ln2_g = (const float*)d_in[12];
  const float* ln2_b = (const float*)d_in[13];
  const float* lnf_g = (const float*)d_in[14];
  const float* lnf_b = (const float*)d_in[15];
  const float* headw = (const float*)d_in[16];

  // workspace carve-up (all bf16 as ushort unless noted)
  unsigned short* ws = (unsigned short*)d_ws;
  unsigned short* wqkvT = ws;                                   // L*3*D*D
  unsigned short* woT   = wqkvT + (size_t)L_*3*D_*D_;           // L*D*D
  unsigned short* w1T   = woT   + (size_t)L_*D_*D_;             // L*DF*D
  unsigned short* w2T   = w1T   + (size_t)L_*D_*DF_;            // L*D*DF
  unsigned short* headT = w2T   + (size_t)L_*D_*DF_;            // V*D
  unsigned short* h     = headT + (size_t)V_*D_;                // M*D
  unsigned short* qkv   = h     + (size_t)M_*D_;                // M*3D
  unsigned short* attno = qkv   + (size_t)M_*3*D_;              // M*D
  unsigned short* h2    = attno + (size_t)M_*D_;                // M*DF
  float*          x     = (float*)(h2 + (size_t)M_*DF_);        // M*D f32

  // ---- weight prep: transpose + cast ----
  transpose_k<<<dim3(D_/32, D_/32, L_), 256, 0, stream>>>(Wq, wqkvT,            D_, D_, (size_t)D_*D_, (size_t)3*D_*D_);
  transpose_k<<<dim3(D_/32, D_/32, L_), 256, 0, stream>>>(Wk, wqkvT + D_*D_,    D_, D_, (size_t)D_*D_, (size_t)3*D_*D_);
  transpose_k<<<dim3(D_/32, D_/32, L_), 256, 0, stream>>>(Wv, wqkvT + 2*D_*D_,  D_, D_, (size_t)D_*D_, (size_t)3*D_*D_);
  transpose_k<<<dim3(D_/32, D_/32, L_), 256, 0, stream>>>(Wo, woT,              D_, D_, (size_t)D_*D_, (size_t)D_*D_);
  transpose_k<<<dim3(DF_/32, D_/32, L_), 256, 0, stream>>>(W1, w1T,             D_, DF_, (size_t)D_*DF_, (size_t)D_*DF_);
  transpose_k<<<dim3(D_/32, DF_/32, L_), 256, 0, stream>>>(W2, w2T,             DF_, D_, (size_t)D_*DF_, (size_t)D_*DF_);
  transpose_k<<<dim3(V_/32, D_/32, 1), 256, 0, stream>>>(headw, headT,          D_, V_, 0, 0);

  // ---- embed ----
  embed_k<<<M_, 256, 0, stream>>>(ids, emb, x);

  // ---- layers ----
  for (int l = 0; l < L_; l++){
    ln_k<<<M_, 256, 0, stream>>>(x, ln1_g + l*D_, ln1_b + l*D_, h);
    gemm_bt<0><<<dim3(3*D_/128, M_/128), 256, 0, stream>>>(h, wqkvT + (size_t)l*3*D_*D_, qkv, nullptr, nullptr, D_, 3*D_);
    attn_k<<<dim3(S_/64, H_, B_), 256, 0, stream>>>(qkv, attno);
    gemm_bt<1><<<dim3(D_/128, M_/128), 256, 0, stream>>>(attno, woT + (size_t)l*D_*D_, x, nullptr, x, D_, D_);
    ln_k<<<M_, 256, 0, stream>>>(x, ln2_g + l*D_, ln2_b + l*D_, h);
    gemm_bt<2><<<dim3(DF_/128, M_/128), 256, 0, stream>>>(h, w1T + (size_t)l*D_*DF_, h2, b1 + l*DF_, nullptr, D_, DF_);
    gemm_bt<3><<<dim3(D_/128, M_/128), 256, 0, stream>>>(h2, w2T + (size_t)l*D_*DF_, x, b2 + l*D_, x, DF_, D_);
  }

  // ---- final LN + head ----
  ln_k<<<M_, 256, 0, stream>>>(x, lnf_g, lnf_b, h);
  gemm_bt<4><<<dim3(V_/128, M_/128), 256, 0, stream>>>(h, headT, (float*)d_out, nullptr, nullptr, D_, V_);
}

// Round 2
// 1087.820 us; speedup vs baseline: 1.2497x; 1.2497x over previous
//
#include <hip/hip_runtime.h>
#include <stdint.h>

// Transformer prefill: B=2,S=1024,V=32000,D=1024,H=16,L=4,DK=64,DF=4096
#define B_ 2
#define S_ 1024
#define V_ 32000
#define D_ 1024
#define H_ 16
#define L_ 4
#define DF_ 4096
#define M_ (B_*S_)

typedef short short8 __attribute__((ext_vector_type(8)));
typedef float f32x4 __attribute__((ext_vector_type(4)));

__device__ __forceinline__ unsigned short f2bf(float f){
  union { float f; unsigned int u; } v; v.f = f;
  unsigned int u = v.u;
  u = u + 0x7fffu + ((u >> 16) & 1u);
  return (unsigned short)(u >> 16);
}

__device__ __forceinline__ void gload16(const void* g, void* l){
  __builtin_amdgcn_global_load_lds(
      (__attribute__((address_space(1))) void*)(uintptr_t)g,
      (__attribute__((address_space(3))) void*)(uintptr_t)l, 16, 0, 0);
}

// ---------------- embed gather: x[row] = emb[ids[row]] (f32) ----------------
__global__ __launch_bounds__(256) void embed_k(const int* __restrict__ ids,
    const float* __restrict__ emb, float* __restrict__ x){
  int row = blockIdx.x;
  int id = ids[row];
  float4 v = reinterpret_cast<const float4*>(emb + (size_t)id*D_)[threadIdx.x];
  reinterpret_cast<float4*>(x + (size_t)row*D_)[threadIdx.x] = v;
}

// ---------------- layernorm row kernel: f32 in -> bf16 out ----------------
__global__ __launch_bounds__(256) void ln_k(const float* __restrict__ x,
    const float* __restrict__ g, const float* __restrict__ b,
    unsigned short* __restrict__ out){
  int row = blockIdx.x;
  int tid = threadIdx.x;
  float4 v = reinterpret_cast<const float4*>(x + (size_t)row*D_)[tid];
  float s = v.x+v.y+v.z+v.w;
  float ss = v.x*v.x + v.y*v.y + v.z*v.z + v.w*v.w;
  #pragma unroll
  for (int off=1; off<64; off<<=1){ s += __shfl_xor(s, off); ss += __shfl_xor(ss, off); }
  __shared__ float rs[4], rss[4];
  int wave = tid>>6, lane = tid&63;
  if (lane==0){ rs[wave]=s; rss[wave]=ss; }
  __syncthreads();
  s  = rs[0]+rs[1]+rs[2]+rs[3];
  ss = rss[0]+rss[1]+rss[2]+rss[3];
  float mean = s * (1.0f/(float)D_);
  float var  = ss * (1.0f/(float)D_) - mean*mean;
  float inv = rsqrtf(var + 1e-5f);
  float4 gg = reinterpret_cast<const float4*>(g)[tid];
  float4 bb = reinterpret_cast<const float4*>(b)[tid];
  ushort4 o;
  o.x = f2bf((v.x-mean)*inv*gg.x + bb.x);
  o.y = f2bf((v.y-mean)*inv*gg.y + bb.y);
  o.z = f2bf((v.z-mean)*inv*gg.z + bb.z);
  o.w = f2bf((v.w-mean)*inv*gg.w + bb.w);
  reinterpret_cast<ushort4*>(out + (size_t)row*D_)[tid] = o;
}

// ---------------- transpose + f32->bf16: in [K][N] -> out [N][K] ----------------
// 64x64 tiles, float4 loads, ushort4 stores
__global__ __launch_bounds__(256) void transpose_k(const float* __restrict__ in,
    unsigned short* __restrict__ out, int K, int N, size_t in_ls, size_t out_ls){
  __shared__ float t[64][65];
  const float* inp = in + (size_t)blockIdx.z*in_ls;
  unsigned short* outp = out + (size_t)blockIdx.z*out_ls;
  int k0 = blockIdx.y*64, n0 = blockIdx.x*64;
  int rr = threadIdx.x >> 4, c4 = (threadIdx.x & 15)*4;
  #pragma unroll
  for (int i=0;i<4;i++){
    float4 v = *reinterpret_cast<const float4*>(inp + (size_t)(k0+rr+i*16)*N + n0 + c4);
    t[rr+i*16][c4+0]=v.x; t[rr+i*16][c4+1]=v.y; t[rr+i*16][c4+2]=v.z; t[rr+i*16][c4+3]=v.w;
  }
  __syncthreads();
  #pragma unroll
  for (int i=0;i<4;i++){
    int n = rr + i*16;
    ushort4 o;
    o.x = f2bf(t[c4+0][n]); o.y = f2bf(t[c4+1][n]);
    o.z = f2bf(t[c4+2][n]); o.w = f2bf(t[c4+3][n]);
    *reinterpret_cast<ushort4*>(outp + (size_t)(n0+n)*K + k0 + c4) = o;
  }
}

// ---------------- GEMM: C[M,N] = A[M,K](bf16) @ B_T[N,K](bf16)^T ----------------
// 1-D grid (x = tiles, XCD-chunk-swizzled, M-blocks innermost), z = split-K chunk.
// EP: 0 = write bf16; 1 = +resid write f32; 2 = +bias,GELU write bf16;
//     3 = +bias,+resid write f32; 4 = write f32; 5 = f32 partial (+z*M*ldc)
template<int EP>
__global__ __launch_bounds__(256)
void gemm_bt(const unsigned short* __restrict__ A, const unsigned short* __restrict__ B,
             void* __restrict__ C, const float* __restrict__ bias,
             const float* __restrict__ resid, int K, int ldc, int MB, int kLen){
  __shared__ unsigned short As[128*64];
  __shared__ unsigned short Bs[128*64];
  const int tid = threadIdx.x;
  const int wave = tid>>6, lane = tid&63;
  const int wm = wave>>1, wn = wave&1;
  const int nwg = gridDim.x;
  const int p = blockIdx.x;
  const int t = (nwg & 7) ? p : ((p & 7)*(nwg>>3) + (p>>3));  // XCD-chunked, bijective (nwg%8==0)
  const int by = t % MB, bx = t / MB;                          // M innermost -> B-panel L2 reuse
  const int row0 = by*128, col0 = bx*128;
  const int kz = blockIdx.z;
  const int k0 = kz*kLen;
  f32x4 acc[4][4] = {};
  // pre-swizzled global source so LDS holds XOR-swizzled rows (rule #21: both sides)
  const int sw8 = ((lane&7) ^ ((lane>>3)&7))*8;
  const unsigned short* Ag = A + (size_t)(row0 + wave*8 + (lane>>3))*K + sw8;
  const unsigned short* Bg = B + (size_t)(col0 + wave*8 + (lane>>3))*K + sw8;
  unsigned short* Asb = As + (wave*8)*64;
  unsigned short* Bsb = Bs + (wave*8)*64;
  const int r = lane&15, g16 = lane>>4;
  const int rsw = (r&7)<<4;
  for (int kt=k0; kt<k0+kLen; kt+=64){
    #pragma unroll
    for (int i=0;i<4;i++){
      gload16(Ag + (size_t)i*32*K + kt, Asb + i*32*64);
      gload16(Bg + (size_t)i*32*K + kt, Bsb + i*32*64);
    }
    __syncthreads();
    #pragma unroll
    for (int ks=0; ks<2; ks++){
      short8 a[4], b[4];
      #pragma unroll
      for (int m=0;m<4;m++)
        a[m] = *reinterpret_cast<const short8*>((const char*)As + (wm*64+m*16+r)*128 + ((ks*64 + g16*16) ^ rsw));
      #pragma unroll
      for (int n=0;n<4;n++)
        b[n] = *reinterpret_cast<const short8*>((const char*)Bs + (wn*64+n*16+r)*128 + ((ks*64 + g16*16) ^ rsw));
      #pragma unroll
      for (int m=0;m<4;m++)
        #pragma unroll
        for (int n=0;n<4;n++)
          acc[m][n] = __builtin_amdgcn_mfma_f32_16x16x32_bf16(a[m], b[n], acc[m][n], 0,0,0);
    }
    __syncthreads();
  }
  float* Cp5 = (float*)C + (size_t)kz*M_*ldc;
  #pragma unroll
  for (int m=0;m<4;m++){
    const int row = row0 + wm*64 + m*16 + g16*4;
    #pragma unroll
    for (int n=0;n<4;n++){
      const int col = col0 + wn*64 + n*16 + r;
      #pragma unroll
      for (int j=0;j<4;j++){
        float val = acc[m][n][j];
        size_t idx = (size_t)(row+j)*ldc + col;
        if constexpr (EP==2 || EP==3) val += bias[col];
        if constexpr (EP==2) val = 0.5f*val*(1.0f + erff(val*0.70710678118f));
        if constexpr (EP==1 || EP==3) val += resid[idx];
        if constexpr (EP==0 || EP==2) ((unsigned short*)C)[idx] = f2bf(val);
        else if constexpr (EP==5) Cp5[idx] = val;
        else ((float*)C)[idx] = val;
      }
    }
  }
}

// ---------------- split-K reduce: x += sum_z part[z] (+ bias) ----------------
__global__ __launch_bounds__(256) void reduce_k(float* __restrict__ x,
    const float* __restrict__ part, const float* __restrict__ bias, int ldc, int KS){
  size_t idx = (size_t)blockIdx.x*256 + threadIdx.x;   // float4 index
  float4 v = reinterpret_cast<const float4*>(part)[idx];
  for (int z=1; z<KS; z++){
    float4 p = reinterpret_cast<const float4*>(part)[(size_t)z*((size_t)M_*ldc/4) + idx];
    v.x+=p.x; v.y+=p.y; v.z+=p.z; v.w+=p.w;
  }
  if (bias){
    float4 b = reinterpret_cast<const float4*>(bias)[idx % (size_t)(ldc/4)];
    v.x+=b.x; v.y+=b.y; v.z+=b.z; v.w+=b.w;
  }
  float4 xx = reinterpret_cast<float4*>(x)[idx];
  v.x+=xx.x; v.y+=xx.y; v.z+=xx.z; v.w+=xx.w;
  reinterpret_cast<float4*>(x)[idx] = v;
}

// ---------------- fused causal attention (flash-style) ----------------
// qkv: [M_][3*D_] bf16 (q | k | v), o: [M_][D_] bf16
__global__ __launch_bounds__(256)
void attn_k(const unsigned short* __restrict__ qkv, unsigned short* __restrict__ o){
  __shared__ unsigned short Ks[64*64];
  __shared__ unsigned short Vt[64*64];
  __shared__ unsigned short Ps[4*16*64];
  const int tid = threadIdx.x;
  const int wave = tid>>6, lane = tid&63;
  const int qb = blockIdx.x, h = blockIdx.y, b = blockIdx.z;
  const int r = lane&15, g = lane>>4;
  const size_t rowbase = (size_t)b*S_*3*D_;
  short8 qf[2];
  {
    const unsigned short* qp = qkv + rowbase + (size_t)(qb*64 + wave*16 + r)*(3*D_) + h*64 + g*8;
    qf[0] = *reinterpret_cast<const short8*>(qp);
    qf[1] = *reinterpret_cast<const short8*>(qp + 32);
  }
  float mrow[4] = {-INFINITY,-INFINITY,-INFINITY,-INFINITY};
  float lrow[4] = {0.f,0.f,0.f,0.f};
  f32x4 oacc[4] = {};
  const int qglob0 = qb*64 + wave*16 + g*4;
  unsigned short* Pw = Ps + wave*16*64;

  for (int kt=0; kt<=qb; kt++){
    __syncthreads();
    #pragma unroll
    for (int i=0;i<2;i++){
      int key = i*32 + (tid>>3);
      int c8 = (tid&7)*8;
      const unsigned short* kp = qkv + rowbase + (size_t)(kt*64+key)*(3*D_) + D_ + h*64 + c8;
      uint4 kd = *reinterpret_cast<const uint4*>(kp);
      int bo = (key*128 + c8*2) ^ ((key&7)<<4);
      *reinterpret_cast<uint4*>((char*)Ks + bo) = kd;
      const unsigned short* vp = qkv + rowbase + (size_t)(kt*64+key)*(3*D_) + 2*D_ + h*64 + c8;
      uint4 vd = *reinterpret_cast<const uint4*>(vp);
      const unsigned short* ve = reinterpret_cast<const unsigned short*>(&vd);
      #pragma unroll
      for (int j=0;j<8;j++){
        int d = c8 + j;
        int bo2 = (d*128 + key*2) ^ ((d&7)<<4);
        *reinterpret_cast<unsigned short*>((char*)Vt + bo2) = ve[j];
      }
    }
    __syncthreads();
    // QK^T -> per-lane scores for q rows (g*4+j), keys (nb*16+r)
    f32x4 sacc[4] = {};
    #pragma unroll
    for (int ks=0; ks<2; ks++){
      #pragma unroll
      for (int nb=0; nb<4; nb++){
        int key = nb*16 + r;
        int bo = (key*128 + (ks*32+g*8)*2) ^ ((key&7)<<4);
        short8 kf = *reinterpret_cast<const short8*>((char*)Ks + bo);
        sacc[nb] = __builtin_amdgcn_mfma_f32_16x16x32_bf16(qf[ks], kf, sacc[nb], 0,0,0);
      }
    }
    float sv[4][4];
    float tm[4] = {-INFINITY,-INFINITY,-INFINITY,-INFINITY};
    #pragma unroll
    for (int nb=0; nb<4; nb++){
      int key = kt*64 + nb*16 + r;
      #pragma unroll
      for (int j=0;j<4;j++){
        float s = sacc[nb][j]*0.125f;
        s = (key <= qglob0 + j) ? s : -INFINITY;
        sv[nb][j] = s;
        tm[j] = fmaxf(tm[j], s);
      }
    }
    #pragma unroll
    for (int off=1; off<16; off<<=1){
      #pragma unroll
      for (int j=0;j<4;j++) tm[j] = fmaxf(tm[j], __shfl_xor(tm[j], off));
    }
    float sf[4], psum[4];
    #pragma unroll
    for (int j=0;j<4;j++){
      float mn = fmaxf(mrow[j], tm[j]);
      sf[j] = __expf(mrow[j]-mn);
      mrow[j] = mn;
      psum[j] = 0.0f;
    }
    #pragma unroll
    for (int nb=0; nb<4; nb++){
      #pragma unroll
      for (int j=0;j<4;j++){
        float p = __expf(sv[nb][j]-mrow[j]);
        psum[j] += p;
        int prow = g*4+j;
        int bo = (prow*128 + (nb*16+r)*2) ^ ((prow&7)<<4);
        *reinterpret_cast<unsigned short*>((char*)Pw + bo) = f2bf(p);
      }
    }
    #pragma unroll
    for (int off=1; off<16; off<<=1){
      #pragma unroll
      for (int j=0;j<4;j++) psum[j] += __shfl_xor(psum[j], off);
    }
    #pragma unroll
    for (int j=0;j<4;j++) lrow[j] = lrow[j]*sf[j] + psum[j];
    #pragma unroll
    for (int nb=0;nb<4;nb++){
      #pragma unroll
      for (int j=0;j<4;j++) oacc[nb][j] *= sf[j];
    }
    asm volatile("s_waitcnt lgkmcnt(0)" ::: "memory");
    // PV: A = P [16q x 64key], B = V^T
    #pragma unroll
    for (int ks=0; ks<2; ks++){
      int bo = (r*128 + (ks*32+g*8)*2) ^ ((r&7)<<4);
      short8 pf = *reinterpret_cast<const short8*>((char*)Pw + bo);
      #pragma unroll
      for (int nb=0; nb<4; nb++){
        int d = nb*16 + r;
        int bo2 = (d*128 + (ks*32+g*8)*2) ^ ((d&7)<<4);
        short8 vf = *reinterpret_cast<const short8*>((char*)Vt + bo2);
        oacc[nb] = __builtin_amdgcn_mfma_f32_16x16x32_bf16(pf, vf, oacc[nb], 0,0,0);
      }
    }
  }
  #pragma unroll
  for (int nb=0; nb<4; nb++){
    #pragma unroll
    for (int j=0;j<4;j++){
      float ov = oacc[nb][j] / lrow[j];
      size_t row = (size_t)b*S_ + qb*64 + wave*16 + g*4 + j;
      o[row*D_ + h*64 + nb*16 + r] = f2bf(ov);
    }
  }
}

extern "C" void kernel_launch(void* const* d_in, const int* in_sizes, int n_in,
                              void* d_out, int out_size, void* d_ws, size_t ws_size,
                              hipStream_t stream) {
  const int*   ids   = (const int*)  d_in[0];
  const float* emb   = (const float*)d_in[1];
  const float* Wq    = (const float*)d_in[2];
  const float* Wk    = (const float*)d_in[3];
  const float* Wv    = (const float*)d_in[4];
  const float* Wo    = (const float*)d_in[5];
  const float* W1    = (const float*)d_in[6];
  const float* b1    = (const float*)d_in[7];
  const float* W2    = (const float*)d_in[8];
  const float* b2    = (const float*)d_in[9];
  const float* ln1_g = (const float*)d_in[10];
  const float* ln1_b = (const float*)d_in[11];
  const float* ln2_g = (const float*)d_in[12];
  const float* ln2_b = (const float*)d_in[13];
  const float* lnf_g = (const float*)d_in[14];
  const float* lnf_b = (const float*)d_in[15];
  const float* headw = (const float*)d_in[16];

  // workspace carve-up (all bf16 as ushort unless noted)
  unsigned short* ws = (unsigned short*)d_ws;
  unsigned short* wqkvT = ws;                                   // L*3*D*D
  unsigned short* woT   = wqkvT + (size_t)L_*3*D_*D_;           // L*D*D
  unsigned short* w1T   = woT   + (size_t)L_*D_*D_;             // L*DF*D
  unsigned short* w2T   = w1T   + (size_t)L_*D_*DF_;            // L*D*DF
  unsigned short* headT = w2T   + (size_t)L_*D_*DF_;            // V*D
  unsigned short* h     = headT + (size_t)V_*D_;                // M*D
  unsigned short* qkv   = h     + (size_t)M_*D_;                // M*3D
  unsigned short* attno = qkv   + (size_t)M_*3*D_;              // M*D
  unsigned short* h2    = attno + (size_t)M_*D_;                // M*DF
  float*          x     = (float*)(h2 + (size_t)M_*DF_);        // M*D f32
  float*          part  = x + (size_t)M_*D_;                    // 4*M*D f32 (split-K partials)
  size_t needed = ((char*)(part + (size_t)4*M_*D_)) - (char*)d_ws;
  const bool splitk = (ws_size >= needed);

  // ---- weight prep: transpose + cast ----
  transpose_k<<<dim3(D_/64, D_/64, L_), 256, 0, stream>>>(Wq, wqkvT,            D_, D_, (size_t)D_*D_, (size_t)3*D_*D_);
  transpose_k<<<dim3(D_/64, D_/64, L_), 256, 0, stream>>>(Wk, wqkvT + D_*D_,    D_, D_, (size_t)D_*D_, (size_t)3*D_*D_);
  transpose_k<<<dim3(D_/64, D_/64, L_), 256, 0, stream>>>(Wv, wqkvT + 2*D_*D_,  D_, D_, (size_t)D_*D_, (size_t)3*D_*D_);
  transpose_k<<<dim3(D_/64, D_/64, L_), 256, 0, stream>>>(Wo, woT,              D_, D_, (size_t)D_*D_, (size_t)D_*D_);
  transpose_k<<<dim3(DF_/64, D_/64, L_), 256, 0, stream>>>(W1, w1T,             D_, DF_, (size_t)D_*DF_, (size_t)D_*DF_);
  transpose_k<<<dim3(D_/64, DF_/64, L_), 256, 0, stream>>>(W2, w2T,             DF_, D_, (size_t)D_*DF_, (size_t)D_*DF_);
  transpose_k<<<dim3(V_/64, D_/64, 1), 256, 0, stream>>>(headw, headT,          D_, V_, 0, 0);

  // ---- embed ----
  embed_k<<<M_, 256, 0, stream>>>(ids, emb, x);

  // ---- layers ----
  for (int l = 0; l < L_; l++){
    ln_k<<<M_, 256, 0, stream>>>(x, ln1_g + l*D_, ln1_b + l*D_, h);
    gemm_bt<0><<<dim3((3*D_/128)*(M_/128), 1, 1), 256, 0, stream>>>(h, wqkvT + (size_t)l*3*D_*D_, qkv, nullptr, nullptr, D_, 3*D_, M_/128, D_);
    attn_k<<<dim3(S_/64, H_, B_), 256, 0, stream>>>(qkv, attno);
    if (splitk){
      gemm_bt<5><<<dim3((D_/128)*(M_/128), 1, 4), 256, 0, stream>>>(attno, woT + (size_t)l*D_*D_, part, nullptr, nullptr, D_, D_, M_/128, D_/4);
      reduce_k<<<(M_*D_/4)/256, 256, 0, stream>>>(x, part, nullptr, D_, 4);
    } else {
      gemm_bt<1><<<dim3((D_/128)*(M_/128), 1, 1), 256, 0, stream>>>(attno, woT + (size_t)l*D_*D_, x, nullptr, x, D_, D_, M_/128, D_);
    }
    ln_k<<<M_, 256, 0, stream>>>(x, ln2_g + l*D_, ln2_b + l*D_, h);
    gemm_bt<2><<<dim3((DF_/128)*(M_/128), 1, 1), 256, 0, stream>>>(h, w1T + (size_t)l*D_*DF_, h2, b1 + l*DF_, nullptr, D_, DF_, M_/128, D_);
    if (splitk){
      gemm_bt<5><<<dim3((D_/128)*(M_/128), 1, 4), 256, 0, stream>>>(h2, w2T + (size_t)l*D_*DF_, part, nullptr, nullptr, DF_, D_, M_/128, DF_/4);
      reduce_k<<<(M_*D_/4)/256, 256, 0, stream>>>(x, part, b2 + l*D_, D_, 4);
    } else {
      gemm_bt<3><<<dim3((D_/128)*(M_/128), 1, 1), 256, 0, stream>>>(h2, w2T + (size_t)l*D_*DF_, x, b2 + l*D_, x, DF_, D_, M_/128, DF_);
    }
  }

  // ---- final LN + head ----
  ln_k<<<M_, 256, 0, stream>>>(x, lnf_g, lnf_b, h);
  gemm_bt<4><<<dim3((V_/128)*(M_/128), 1, 1), 256, 0, stream>>>(h, headT, (float*)d_out, nullptr, nullptr, D_, V_, M_/128, D_);
}

// Round 3
// 1036.004 us; speedup vs baseline: 1.3122x; 1.0500x over previous
//
#include <hip/hip_runtime.h>
#include <stdint.h>

// Transformer prefill: B=2,S=1024,V=32000,D=1024,H=16,L=4,DK=64,DF=4096
#define B_ 2
#define S_ 1024
#define V_ 32000
#define D_ 1024
#define H_ 16
#define L_ 4
#define DF_ 4096
#define M_ (B_*S_)

typedef short short8 __attribute__((ext_vector_type(8)));
typedef float f32x4 __attribute__((ext_vector_type(4)));

__device__ __forceinline__ unsigned short f2bf(float f){
  union { float f; unsigned int u; } v; v.f = f;
  unsigned int u = v.u;
  u = u + 0x7fffu + ((u >> 16) & 1u);
  return (unsigned short)(u >> 16);
}

__device__ __forceinline__ void gload16(const void* g, void* l){
  __builtin_amdgcn_global_load_lds(
      (__attribute__((address_space(1))) void*)(uintptr_t)g,
      (__attribute__((address_space(3))) void*)(uintptr_t)l, 16, 0, 0);
}

// ---------------- embed gather ----------------
__global__ __launch_bounds__(256) void embed_k(const int* __restrict__ ids,
    const float* __restrict__ emb, float* __restrict__ x){
  int row = blockIdx.x;
  int id = ids[row];
  float4 v = reinterpret_cast<const float4*>(emb + (size_t)id*D_)[threadIdx.x];
  reinterpret_cast<float4*>(x + (size_t)row*D_)[threadIdx.x] = v;
}

// ---------------- layernorm: f32 in -> bf16 out ----------------
__global__ __launch_bounds__(256) void ln_k(const float* __restrict__ x,
    const float* __restrict__ g, const float* __restrict__ b,
    unsigned short* __restrict__ out){
  int row = blockIdx.x;
  int tid = threadIdx.x;
  float4 v = reinterpret_cast<const float4*>(x + (size_t)row*D_)[tid];
  float s = v.x+v.y+v.z+v.w;
  float ss = v.x*v.x + v.y*v.y + v.z*v.z + v.w*v.w;
  #pragma unroll
  for (int off=1; off<64; off<<=1){ s += __shfl_xor(s, off); ss += __shfl_xor(ss, off); }
  __shared__ float rs[4], rss[4];
  int wave = tid>>6, lane = tid&63;
  if (lane==0){ rs[wave]=s; rss[wave]=ss; }
  __syncthreads();
  s  = rs[0]+rs[1]+rs[2]+rs[3];
  ss = rss[0]+rss[1]+rss[2]+rss[3];
  float mean = s * (1.0f/(float)D_);
  float var  = ss * (1.0f/(float)D_) - mean*mean;
  float inv = rsqrtf(var + 1e-5f);
  float4 gg = reinterpret_cast<const float4*>(g)[tid];
  float4 bb = reinterpret_cast<const float4*>(b)[tid];
  ushort4 o;
  o.x = f2bf((v.x-mean)*inv*gg.x + bb.x);
  o.y = f2bf((v.y-mean)*inv*gg.y + bb.y);
  o.z = f2bf((v.z-mean)*inv*gg.z + bb.z);
  o.w = f2bf((v.w-mean)*inv*gg.w + bb.w);
  reinterpret_cast<ushort4*>(out + (size_t)row*D_)[tid] = o;
}

// ---------------- transpose + f32->bf16: in [K][N] -> out [N][K] ----------------
__global__ __launch_bounds__(256) void transpose_k(const float* __restrict__ in,
    unsigned short* __restrict__ out, int K, int N, size_t in_ls, size_t out_ls){
  __shared__ float t[64][65];
  const float* inp = in + (size_t)blockIdx.z*in_ls;
  unsigned short* outp = out + (size_t)blockIdx.z*out_ls;
  int k0 = blockIdx.y*64, n0 = blockIdx.x*64;
  int rr = threadIdx.x >> 4, c4 = (threadIdx.x & 15)*4;
  #pragma unroll
  for (int i=0;i<4;i++){
    float4 v = *reinterpret_cast<const float4*>(inp + (size_t)(k0+rr+i*16)*N + n0 + c4);
    t[rr+i*16][c4+0]=v.x; t[rr+i*16][c4+1]=v.y; t[rr+i*16][c4+2]=v.z; t[rr+i*16][c4+3]=v.w;
  }
  __syncthreads();
  #pragma unroll
  for (int i=0;i<4;i++){
    int n = rr + i*16;
    ushort4 o;
    o.x = f2bf(t[c4+0][n]); o.y = f2bf(t[c4+1][n]);
    o.z = f2bf(t[c4+2][n]); o.w = f2bf(t[c4+3][n]);
    *reinterpret_cast<ushort4*>(outp + (size_t)(n0+n)*K + k0 + c4) = o;
  }
}

// ---------------- 128^2 2-phase GEMM (layer GEMMs) ----------------
// EP: 0 = bf16; 1 = +resid f32; 2 = +bias,GELU bf16; 3 = +bias,+resid f32; 5 = f32 partial
template<int EP>
__global__ __launch_bounds__(256)
void gemm_bt(const unsigned short* __restrict__ A, const unsigned short* __restrict__ B,
             void* __restrict__ C, const float* __restrict__ bias,
             const float* __restrict__ resid, int K, int ldc, int MB, int kLen){
  __shared__ unsigned short As[128*64];
  __shared__ unsigned short Bs[128*64];
  const int tid = threadIdx.x;
  const int wave = tid>>6, lane = tid&63;
  const int wm = wave>>1, wn = wave&1;
  const int nwg = gridDim.x;
  const int p = blockIdx.x;
  const int t = (nwg & 7) ? p : ((p & 7)*(nwg>>3) + (p>>3));
  const int by = t % MB, bx = t / MB;
  const int row0 = by*128, col0 = bx*128;
  const int kz = blockIdx.z;
  const int k0 = kz*kLen;
  f32x4 acc[4][4] = {};
  const int sw8 = ((lane&7) ^ ((lane>>3)&7))*8;
  const unsigned short* Ag = A + (size_t)(row0 + wave*8 + (lane>>3))*K + sw8;
  const unsigned short* Bg = B + (size_t)(col0 + wave*8 + (lane>>3))*K + sw8;
  unsigned short* Asb = As + (wave*8)*64;
  unsigned short* Bsb = Bs + (wave*8)*64;
  const int r = lane&15, g16 = lane>>4;
  const int rsw = (r&7)<<4;
  for (int kt=k0; kt<k0+kLen; kt+=64){
    #pragma unroll
    for (int i=0;i<4;i++){
      gload16(Ag + (size_t)i*32*K + kt, Asb + i*32*64);
      gload16(Bg + (size_t)i*32*K + kt, Bsb + i*32*64);
    }
    __syncthreads();
    #pragma unroll
    for (int ks=0; ks<2; ks++){
      short8 a[4], b[4];
      #pragma unroll
      for (int m=0;m<4;m++)
        a[m] = *reinterpret_cast<const short8*>((const char*)As + (wm*64+m*16+r)*128 + ((ks*64 + g16*16) ^ rsw));
      #pragma unroll
      for (int n=0;n<4;n++)
        b[n] = *reinterpret_cast<const short8*>((const char*)Bs + (wn*64+n*16+r)*128 + ((ks*64 + g16*16) ^ rsw));
      #pragma unroll
      for (int m=0;m<4;m++)
        #pragma unroll
        for (int n=0;n<4;n++)
          acc[m][n] = __builtin_amdgcn_mfma_f32_16x16x32_bf16(a[m], b[n], acc[m][n], 0,0,0);
    }
    __syncthreads();
  }
  float* Cp5 = (float*)C + (size_t)kz*M_*ldc;
  #pragma unroll
  for (int m=0;m<4;m++){
    const int row = row0 + wm*64 + m*16 + g16*4;
    #pragma unroll
    for (int n=0;n<4;n++){
      const int col = col0 + wn*64 + n*16 + r;
      #pragma unroll
      for (int j=0;j<4;j++){
        float val = acc[m][n][j];
        size_t idx = (size_t)(row+j)*ldc + col;
        if constexpr (EP==2 || EP==3) val += bias[col];
        if constexpr (EP==2) val = 0.5f*val*(1.0f + erff(val*0.70710678118f));
        if constexpr (EP==1 || EP==3) val += resid[idx];
        if constexpr (EP==0 || EP==2) ((unsigned short*)C)[idx] = f2bf(val);
        else if constexpr (EP==5) Cp5[idx] = val;
        else ((float*)C)[idx] = val;
      }
    }
  }
}

// ---------------- 256^2 8-phase GEMM (head): C[M,N] f32 = A bf16 @ B_T bf16 ----------------
// 512 thr = 8 waves (2M x 4N); BK=64; LDS 128KB double-buffered; counted vmcnt.
#define LDA8(buf,m,ks) (*(const short8*)(lds8 + (buf)*65536 + (wm*128+(m)*16+r)*128 + (((ks)*64+g16*16)^rsw)))
#define LDB8(buf,n,ks) (*(const short8*)(lds8 + (buf)*65536 + 32768 + (wn*64+(n)*16+r)*128 + (((ks)*64+g16*16)^rsw)))
#define STG(buf,isB,h,i,tile) gload16( \
    ((isB) ? Bw + (size_t)(col0 + (h)*128 + (i)*64 + wave*8 + srow)*K + (size_t)(tile)*64 + scsw \
           : A  + (size_t)(row0 + (h)*128 + (i)*64 + wave*8 + srow)*K + (size_t)(tile)*64 + scsw), \
    lds8 + (buf)*65536 + (isB)*32768 + ((h)*128 + (i)*64 + wave*8)*128 )
#define STG_HT(buf,isB,h,tile) do{ STG(buf,isB,h,0,tile); STG(buf,isB,h,1,tile); }while(0)
#define BLOAD8(bT) do{ \
  bfr[0][0]=LDB8(bT,0,0); bfr[0][1]=LDB8(bT,0,1); bfr[1][0]=LDB8(bT,1,0); bfr[1][1]=LDB8(bT,1,1); \
  bfr[2][0]=LDB8(bT,2,0); bfr[2][1]=LDB8(bT,2,1); bfr[3][0]=LDB8(bT,3,0); bfr[3][1]=LDB8(bT,3,1); }while(0)
#define MM8(mb,n) do{ \
  acc[mb][n]    =__builtin_amdgcn_mfma_f32_16x16x32_bf16(a0[0],bfr[n][0],acc[mb][n],0,0,0); \
  acc[mb][n]    =__builtin_amdgcn_mfma_f32_16x16x32_bf16(a0[1],bfr[n][1],acc[mb][n],0,0,0); \
  acc[(mb)+1][n]=__builtin_amdgcn_mfma_f32_16x16x32_bf16(a1[0],bfr[n][0],acc[(mb)+1][n],0,0,0); \
  acc[(mb)+1][n]=__builtin_amdgcn_mfma_f32_16x16x32_bf16(a1[1],bfr[n][1],acc[(mb)+1][n],0,0,0); }while(0)
#define PH8(bT, mb, STAGES, TAIL) do{ \
  short8 a0[2], a1[2]; \
  a0[0]=LDA8(bT,mb,0); a0[1]=LDA8(bT,mb,1); a1[0]=LDA8(bT,(mb)+1,0); a1[1]=LDA8(bT,(mb)+1,1); \
  STAGES; \
  __builtin_amdgcn_s_barrier(); \
  asm volatile("s_waitcnt lgkmcnt(0)" ::: "memory"); \
  __builtin_amdgcn_sched_barrier(0); \
  __builtin_amdgcn_s_setprio(1); \
  MM8(mb,0); MM8(mb,1); MM8(mb,2); MM8(mb,3); \
  __builtin_amdgcn_s_setprio(0); \
  TAIL; \
  __builtin_amdgcn_s_barrier(); \
  __builtin_amdgcn_sched_barrier(0); \
}while(0)

__global__ __launch_bounds__(512, 2)
void gemm_8ph(const unsigned short* __restrict__ A, const unsigned short* __restrict__ Bw,
              float* __restrict__ C, int K, int ldc, int MB){
  __shared__ char lds8[131072];
  const int tid = threadIdx.x;
  const int wave = tid>>6, lane = tid&63;
  const int wm = wave>>2, wn = wave&3;
  const int nwg = gridDim.x;
  const int pp = blockIdx.x;
  const int t = (nwg & 7) ? pp : ((pp & 7)*(nwg>>3) + (pp>>3));
  const int by = t % MB, bx = t / MB;
  const int row0 = by*256, col0 = bx*256;
  const int r = lane&15, g16 = lane>>4;
  const int rsw = (r&7)<<4;
  const int srow = lane>>3;
  const int scsw = ((lane&7) ^ srow)*8;

  f32x4 acc[8][4] = {};
  short8 bfr[4][2];
  const int NT = K/64;

  // prologue: t0 fully -> buf0; t1.B -> buf1
  STG_HT(0,1,0, 0); STG_HT(0,1,1, 0);
  STG_HT(0,0,0, 0); STG_HT(0,0,1, 0);
  STG_HT(1,1,0, 1); STG_HT(1,1,1, 1);
  asm volatile("s_waitcnt vmcnt(4)" ::: "memory");
  __builtin_amdgcn_s_barrier();
  __builtin_amdgcn_sched_barrier(0);

  for (int T0 = 0; T0 < NT; T0 += 2){
    const bool lastit = (T0 + 2 >= NT);
    // ---- q=0: tile T0 from buf0 ----
    BLOAD8(0);
    PH8(0, 0, STG_HT(1,0,0, T0+1), ((void)0));                        // ph1: t1.A0
    PH8(0, 2, { STG_HT(1,0,1, T0+1); if(!lastit) STG_HT(0,1,0, T0+2); }, ((void)0)); // ph2
    PH8(0, 4, { if(!lastit) STG_HT(0,1,1, T0+2); }, ((void)0));        // ph3: t2.B1
    if (lastit)
      PH8(0, 6, ((void)0), asm volatile("s_waitcnt vmcnt(0)" ::: "memory"));  // ph4 + W1
    else
      PH8(0, 6, ((void)0), asm volatile("s_waitcnt vmcnt(4)" ::: "memory"));
    // ---- q=1: tile T0+1 from buf1 ----
    BLOAD8(1);
    PH8(1, 0, { if(!lastit) STG_HT(0,0,0, T0+2); }, ((void)0));        // ph5: t2.A0
    PH8(1, 2, { if(!lastit) STG_HT(0,0,1, T0+2); }, ((void)0));        // ph6: t2.A1
    PH8(1, 4, { if(!lastit) STG_HT(1,1,0, T0+3); }, ((void)0));        // ph7: t3.B0
    if (lastit)
      PH8(1, 6, ((void)0), ((void)0));                                 // ph8 (no wait)
    else
      PH8(1, 6, STG_HT(1,1,1, T0+3), asm volatile("s_waitcnt vmcnt(4)" ::: "memory")); // ph8 + W2
  }

  #pragma unroll
  for (int m=0;m<8;m++){
    const int row = row0 + wm*128 + m*16 + g16*4;
    #pragma unroll
    for (int n=0;n<4;n++){
      const int col = col0 + wn*64 + n*16 + r;
      #pragma unroll
      for (int j=0;j<4;j++)
        C[(size_t)(row+j)*ldc + col] = acc[m][n][j];
    }
  }
}

// ---------------- split-K reduce ----------------
__global__ __launch_bounds__(256) void reduce_k(float* __restrict__ x,
    const float* __restrict__ part, const float* __restrict__ bias, int ldc, int KS){
  size_t idx = (size_t)blockIdx.x*256 + threadIdx.x;
  float4 v = reinterpret_cast<const float4*>(part)[idx];
  for (int z=1; z<KS; z++){
    float4 p = reinterpret_cast<const float4*>(part)[(size_t)z*((size_t)M_*ldc/4) + idx];
    v.x+=p.x; v.y+=p.y; v.z+=p.z; v.w+=p.w;
  }
  if (bias){
    float4 b = reinterpret_cast<const float4*>(bias)[idx % (size_t)(ldc/4)];
    v.x+=b.x; v.y+=b.y; v.z+=b.z; v.w+=b.w;
  }
  float4 xx = reinterpret_cast<float4*>(x)[idx];
  v.x+=xx.x; v.y+=xx.y; v.z+=xx.z; v.w+=xx.w;
  reinterpret_cast<float4*>(x)[idx] = v;
}

// ---------------- fused causal attention (flash-style) ----------------
__global__ __launch_bounds__(256)
void attn_k(const unsigned short* __restrict__ qkv, unsigned short* __restrict__ o){
  __shared__ unsigned short Ks[64*64];
  __shared__ unsigned short Vt[64*64];
  __shared__ unsigned short Ps[4*16*64];
  const int tid = threadIdx.x;
  const int wave = tid>>6, lane = tid&63;
  const int qb = blockIdx.x, h = blockIdx.y, b = blockIdx.z;
  const int r = lane&15, g = lane>>4;
  const size_t rowbase = (size_t)b*S_*3*D_;
  short8 qf[2];
  {
    const unsigned short* qp = qkv + rowbase + (size_t)(qb*64 + wave*16 + r)*(3*D_) + h*64 + g*8;
    qf[0] = *reinterpret_cast<const short8*>(qp);
    qf[1] = *reinterpret_cast<const short8*>(qp + 32);
  }
  float mrow[4] = {-INFINITY,-INFINITY,-INFINITY,-INFINITY};
  float lrow[4] = {0.f,0.f,0.f,0.f};
  f32x4 oacc[4] = {};
  const int qglob0 = qb*64 + wave*16 + g*4;
  unsigned short* Pw = Ps + wave*16*64;

  for (int kt=0; kt<=qb; kt++){
    __syncthreads();
    #pragma unroll
    for (int i=0;i<2;i++){
      int key = i*32 + (tid>>3);
      int c8 = (tid&7)*8;
      const unsigned short* kp = qkv + rowbase + (size_t)(kt*64+key)*(3*D_) + D_ + h*64 + c8;
      uint4 kd = *reinterpret_cast<const uint4*>(kp);
      int bo = (key*128 + c8*2) ^ ((key&7)<<4);
      *reinterpret_cast<uint4*>((char*)Ks + bo) = kd;
      const unsigned short* vp = qkv + rowbase + (size_t)(kt*64+key)*(3*D_) + 2*D_ + h*64 + c8;
      uint4 vd = *reinterpret_cast<const uint4*>(vp);
      const unsigned short* ve = reinterpret_cast<const unsigned short*>(&vd);
      #pragma unroll
      for (int j=0;j<8;j++){
        int d = c8 + j;
        int bo2 = (d*128 + key*2) ^ ((d&7)<<4);
        *reinterpret_cast<unsigned short*>((char*)Vt + bo2) = ve[j];
      }
    }
    __syncthreads();
    f32x4 sacc[4] = {};
    #pragma unroll
    for (int ks=0; ks<2; ks++){
      #pragma unroll
      for (int nb=0; nb<4; nb++){
        int key = nb*16 + r;
        int bo = (key*128 + (ks*32+g*8)*2) ^ ((key&7)<<4);
        short8 kf = *reinterpret_cast<const short8*>((char*)Ks + bo);
        sacc[nb] = __builtin_amdgcn_mfma_f32_16x16x32_bf16(qf[ks], kf, sacc[nb], 0,0,0);
      }
    }
    float sv[4][4];
    float tm[4] = {-INFINITY,-INFINITY,-INFINITY,-INFINITY};
    #pragma unroll
    for (int nb=0; nb<4; nb++){
      int key = kt*64 + nb*16 + r;
      #pragma unroll
      for (int j=0;j<4;j++){
        float s = sacc[nb][j]*0.125f;
        s = (key <= qglob0 + j) ? s : -INFINITY;
        sv[nb][j] = s;
        tm[j] = fmaxf(tm[j], s);
      }
    }
    #pragma unroll
    for (int off=1; off<16; off<<=1){
      #pragma unroll
      for (int j=0;j<4;j++) tm[j] = fmaxf(tm[j], __shfl_xor(tm[j], off));
    }
    float sf[4], psum[4];
    #pragma unroll
    for (int j=0;j<4;j++){
      float mn = fmaxf(mrow[j], tm[j]);
      sf[j] = __expf(mrow[j]-mn);
      mrow[j] = mn;
      psum[j] = 0.0f;
    }
    #pragma unroll
    for (int nb=0; nb<4; nb++){
      #pragma unroll
      for (int j=0;j<4;j++){
        float p = __expf(sv[nb][j]-mrow[j]);
        psum[j] += p;
        int prow = g*4+j;
        int bo = (prow*128 + (nb*16+r)*2) ^ ((prow&7)<<4);
        *reinterpret_cast<unsigned short*>((char*)Pw + bo) = f2bf(p);
      }
    }
    #pragma unroll
    for (int off=1; off<16; off<<=1){
      #pragma unroll
      for (int j=0;j<4;j++) psum[j] += __shfl_xor(psum[j], off);
    }
    #pragma unroll
    for (int j=0;j<4;j++) lrow[j] = lrow[j]*sf[j] + psum[j];
    #pragma unroll
    for (int nb=0;nb<4;nb++){
      #pragma unroll
      for (int j=0;j<4;j++) oacc[nb][j] *= sf[j];
    }
    asm volatile("s_waitcnt lgkmcnt(0)" ::: "memory");
    #pragma unroll
    for (int ks=0; ks<2; ks++){
      int bo = (r*128 + (ks*32+g*8)*2) ^ ((r&7)<<4);
      short8 pf = *reinterpret_cast<const short8*>((char*)Pw + bo);
      #pragma unroll
      for (int nb=0; nb<4; nb++){
        int d = nb*16 + r;
        int bo2 = (d*128 + (ks*32+g*8)*2) ^ ((d&7)<<4);
        short8 vf = *reinterpret_cast<const short8*>((char*)Vt + bo2);
        oacc[nb] = __builtin_amdgcn_mfma_f32_16x16x32_bf16(pf, vf, oacc[nb], 0,0,0);
      }
    }
  }
  #pragma unroll
  for (int nb=0; nb<4; nb++){
    #pragma unroll
    for (int j=0;j<4;j++){
      float ov = oacc[nb][j] / lrow[j];
      size_t row = (size_t)b*S_ + qb*64 + wave*16 + g*4 + j;
      o[row*D_ + h*64 + nb*16 + r] = f2bf(ov);
    }
  }
}

extern "C" void kernel_launch(void* const* d_in, const int* in_sizes, int n_in,
                              void* d_out, int out_size, void* d_ws, size_t ws_size,
                              hipStream_t stream) {
  const int*   ids   = (const int*)  d_in[0];
  const float* emb   = (const float*)d_in[1];
  const float* Wq    = (const float*)d_in[2];
  const float* Wk    = (const float*)d_in[3];
  const float* Wv    = (const float*)d_in[4];
  const float* Wo    = (const float*)d_in[5];
  const float* W1    = (const float*)d_in[6];
  const float* b1    = (const float*)d_in[7];
  const float* W2    = (const float*)d_in[8];
  const float* b2    = (const float*)d_in[9];
  const float* ln1_g = (const float*)d_in[10];
  const float* ln1_b = (const float*)d_in[11];
  const float* ln2_g = (const float*)d_in[12];
  const float* ln2_b = (const float*)d_in[13];
  const float* lnf_g = (const float*)d_in[14];
  const float* lnf_b = (const float*)d_in[15];
  const float* headw = (const float*)d_in[16];

  unsigned short* ws = (unsigned short*)d_ws;
  unsigned short* wqkvT = ws;                                   // L*3*D*D
  unsigned short* woT   = wqkvT + (size_t)L_*3*D_*D_;           // L*D*D
  unsigned short* w1T   = woT   + (size_t)L_*D_*D_;             // L*DF*D
  unsigned short* w2T   = w1T   + (size_t)L_*D_*DF_;            // L*D*DF
  unsigned short* headT = w2T   + (size_t)L_*D_*DF_;            // V*D
  unsigned short* h     = headT + (size_t)V_*D_;                // M*D
  unsigned short* qkv   = h     + (size_t)M_*D_;                // M*3D
  unsigned short* attno = qkv   + (size_t)M_*3*D_;              // M*D
  unsigned short* h2    = attno + (size_t)M_*D_;                // M*DF
  float*          x     = (float*)(h2 + (size_t)M_*DF_);        // M*D f32
  float*          part  = x + (size_t)M_*D_;                    // 4*M*D f32
  size_t needed = ((char*)(part + (size_t)4*M_*D_)) - (char*)d_ws;
  const bool splitk = (ws_size >= needed);

  // ---- weight prep ----
  transpose_k<<<dim3(D_/64, D_/64, L_), 256, 0, stream>>>(Wq, wqkvT,            D_, D_, (size_t)D_*D_, (size_t)3*D_*D_);
  transpose_k<<<dim3(D_/64, D_/64, L_), 256, 0, stream>>>(Wk, wqkvT + D_*D_,    D_, D_, (size_t)D_*D_, (size_t)3*D_*D_);
  transpose_k<<<dim3(D_/64, D_/64, L_), 256, 0, stream>>>(Wv, wqkvT + 2*D_*D_,  D_, D_, (size_t)D_*D_, (size_t)3*D_*D_);
  transpose_k<<<dim3(D_/64, D_/64, L_), 256, 0, stream>>>(Wo, woT,              D_, D_, (size_t)D_*D_, (size_t)D_*D_);
  transpose_k<<<dim3(DF_/64, D_/64, L_), 256, 0, stream>>>(W1, w1T,             D_, DF_, (size_t)D_*DF_, (size_t)D_*DF_);
  transpose_k<<<dim3(D_/64, DF_/64, L_), 256, 0, stream>>>(W2, w2T,             DF_, D_, (size_t)D_*DF_, (size_t)D_*DF_);
  transpose_k<<<dim3(V_/64, D_/64, 1), 256, 0, stream>>>(headw, headT,          D_, V_, 0, 0);

  // ---- embed ----
  embed_k<<<M_, 256, 0, stream>>>(ids, emb, x);

  // ---- layers ----
  for (int l = 0; l < L_; l++){
    ln_k<<<M_, 256, 0, stream>>>(x, ln1_g + l*D_, ln1_b + l*D_, h);
    gemm_bt<0><<<dim3((3*D_/128)*(M_/128), 1, 1), 256, 0, stream>>>(h, wqkvT + (size_t)l*3*D_*D_, qkv, nullptr, nullptr, D_, 3*D_, M_/128, D_);
    attn_k<<<dim3(S_/64, H_, B_), 256, 0, stream>>>(qkv, attno);
    if (splitk){
      gemm_bt<5><<<dim3((D_/128)*(M_/128), 1, 4), 256, 0, stream>>>(attno, woT + (size_t)l*D_*D_, part, nullptr, nullptr, D_, D_, M_/128, D_/4);
      reduce_k<<<(M_*D_/4)/256, 256, 0, stream>>>(x, part, nullptr, D_, 4);
    } else {
      gemm_bt<1><<<dim3((D_/128)*(M_/128), 1, 1), 256, 0, stream>>>(attno, woT + (size_t)l*D_*D_, x, nullptr, x, D_, D_, M_/128, D_);
    }
    ln_k<<<M_, 256, 0, stream>>>(x, ln2_g + l*D_, ln2_b + l*D_, h);
    gemm_bt<2><<<dim3((DF_/128)*(M_/128), 1, 1), 256, 0, stream>>>(h, w1T + (size_t)l*D_*DF_, h2, b1 + l*DF_, nullptr, D_, DF_, M_/128, D_);
    if (splitk){
      gemm_bt<5><<<dim3((D_/128)*(M_/128), 1, 4), 256, 0, stream>>>(h2, w2T + (size_t)l*D_*DF_, part, nullptr, nullptr, DF_, D_, M_/128, DF_/4);
      reduce_k<<<(M_*D_/4)/256, 256, 0, stream>>>(x, part, b2 + l*D_, D_, 4);
    } else {
      gemm_bt<3><<<dim3((D_/128)*(M_/128), 1, 1), 256, 0, stream>>>(h2, w2T + (size_t)l*D_*DF_, x, b2 + l*D_, x, DF_, D_, M_/128, DF_);
    }
  }

  // ---- final LN + 8-phase head GEMM ----
  ln_k<<<M_, 256, 0, stream>>>(x, lnf_g, lnf_b, h);
  gemm_8ph<<<dim3((V_/256)*(M_/256), 1, 1), 512, 0, stream>>>(h, headT, (float*)d_out, D_, V_, M_/256);
}